// Round 3
// baseline (3007.021 us; speedup 1.0000x reference)
//
#include <hip/hip_runtime.h>

// Dims: B=16, H=W=64, C_OUT=64, C_IN=32, S(n_out)=10, 3x3 SAME conv adjoint.
// Inputs FP32, output FP32 (fp32 confirmed by round-2 forensics: bias-scale
// value 6.557 appeared at fp32 element 10.48M = byte 41.94M = where our bf16
// bu landed — output buffer is read as fp32).
// Input  w_out[b, 0, (h*64+w)*64+co, s]  : per (b,pixel) contiguous 640 fp32 (co major, s minor)
// Output w_new[b, 0, (h*64+w)*32+ci, s]  : per (b,pixel) contiguous 320 fp32 (ci major, s minor)
// y[b,s,h,w,ci] = sum_{i,j,co} z[b,s,h+1-i,w+1-j,co] * K[i,j,ci,co]
// b_contrib[b,s] = sum_{h,w,co} z[b,s,h,w,co] * bias[co]

typedef unsigned int uint;
typedef unsigned short ushort;

#define OUT_BU_OFF 20971520u   // 16*131072*10  (fp32 elements)
#define OUT_WL_OFF 20971680u
#define OUT_BL_OFF 41943200u
#define IN_PER_B   2621440u    // 4096*640 (fp32 elements)

__device__ __forceinline__ float bf_lo(uint u) { return __uint_as_float(u << 16); }
__device__ __forceinline__ float bf_hi(uint u) { return __uint_as_float(u & 0xffff0000u); }
__device__ __forceinline__ ushort f2bf(float f) {
    uint x = __float_as_uint(f);
    x += 0x7fffu + ((x >> 16) & 1u);   // RNE
    return (ushort)(x >> 16);
}

// ---------------- conv adjoint kernel ----------------
// grid: 2048 = 2 sets * 16 b * 64 h ; block: 256 = 8 px-groups * 32 ci
__global__ __launch_bounds__(256) void conv_kernel(
    const float* __restrict__ inU, const float* __restrict__ inL,
    const float* __restrict__ Kg, float* __restrict__ out)
{
    // [tap][cop][ci] -> packed pair (bf16(K[tap,ci,2cop]) | bf16(K[tap,ci,2cop+1])<<16)
    __shared__ uint lk2[9 * 32 * 32];   // 36,864 B
    const int tid = threadIdx.x;

    for (int d = tid; d < 9 * 32 * 32; d += 256) {
        int tap = d >> 10;          // d / 1024
        int cop = (d >> 5) & 31;
        int ci  = d & 31;
        float k0 = Kg[tap * 2048 + ci * 64 + 2 * cop];
        float k1 = Kg[tap * 2048 + ci * 64 + 2 * cop + 1];
        lk2[tap * 1024 + cop * 32 + ci] = (uint)f2bf(k0) | ((uint)f2bf(k1) << 16);
    }
    __syncthreads();

    const int blk = blockIdx.x;
    const int h   = blk & 63;
    const int b   = (blk >> 6) & 15;
    const int set = blk >> 10;

    const float* in   = set ? inL : inU;
    float*       outw = out + (set ? OUT_WL_OFF : 0u);

    const int ci = tid & 31;
    const int px = tid >> 5;        // 0..7
    const float* inb = in + (size_t)b * IN_PER_B;

    for (int wt = 0; wt < 8; ++wt) {
        const int w = wt * 8 + px;
        float acc[10];
#pragma unroll
        for (int s = 0; s < 10; ++s) acc[s] = 0.f;

#pragma unroll
        for (int i = 0; i < 3; ++i) {
            const int sh = h + 1 - i;
            if ((unsigned)sh < 64u) {
#pragma unroll
                for (int j = 0; j < 3; ++j) {
                    const int sw = w + 1 - j;
                    if ((unsigned)sw < 64u) {
                        const float* p  = inb + (size_t)(sh * 64 + sw) * 640u;
                        const uint*  kp = lk2 + (i * 3 + j) * 1024 + ci;
#pragma unroll 2
                        for (int cop = 0; cop < 32; ++cop) {
                            const uint kk = kp[cop * 32];
                            const float kf0 = bf_lo(kk);
                            const float kf1 = bf_hi(kk);
                            const float4* q = (const float4*)(p + cop * 20);  // 80*cop B: 16B aligned
                            float4 a0 = q[0], a1 = q[1], a2 = q[2], a3 = q[3], a4 = q[4];
                            acc[0] += a0.x * kf0;  acc[1] += a0.y * kf0;
                            acc[2] += a0.z * kf0;  acc[3] += a0.w * kf0;
                            acc[4] += a1.x * kf0;  acc[5] += a1.y * kf0;
                            acc[6] += a1.z * kf0;  acc[7] += a1.w * kf0;
                            acc[8] += a2.x * kf0;  acc[9] += a2.y * kf0;
                            acc[0] += a2.z * kf1;  acc[1] += a2.w * kf1;
                            acc[2] += a3.x * kf1;  acc[3] += a3.y * kf1;
                            acc[4] += a3.z * kf1;  acc[5] += a3.w * kf1;
                            acc[6] += a4.x * kf1;  acc[7] += a4.y * kf1;
                            acc[8] += a4.z * kf1;  acc[9] += a4.w * kf1;
                        }
                    }
                }
            }
        }

        // out[(b*131072 + (h*64+w)*32 + ci)*10 + s], fp32; byte offset 40*X -> 8B aligned
        const size_t obase = ((size_t)b * 131072u + (size_t)(h * 64 + w) * 32u + (size_t)ci) * 10u;
        float2* op = (float2*)(outw + obase);
        op[0] = make_float2(acc[0], acc[1]);
        op[1] = make_float2(acc[2], acc[3]);
        op[2] = make_float2(acc[4], acc[5]);
        op[3] = make_float2(acc[6], acc[7]);
        op[4] = make_float2(acc[8], acc[9]);
    }
}

// ---------------- bias-contribution partial reduction ----------------
// grid: 256 = 2 sets * 16 b * 8 pixel-chunks ; block: 640 threads (tid == co*10+s)
__global__ __launch_bounds__(640) void bias_kernel(
    const float* __restrict__ inU, const float* __restrict__ inL,
    const float* __restrict__ bias, float* __restrict__ ws)
{
    __shared__ float red[640];
    const int tid   = threadIdx.x;
    const int blk   = blockIdx.x;
    const int chunk = blk & 7;
    const int b     = (blk >> 3) & 15;
    const int set   = blk >> 7;

    const float* in = set ? inL : inU;
    const float  bf = bias[tid / 10];
    const float* p  = in + (size_t)b * IN_PER_B + (size_t)chunk * 512u * 640u;

    float acc = 0.f;
    for (int it = 0; it < 512; ++it) {
        acc += p[(size_t)it * 640u + tid] * bf;
    }
    red[tid] = acc;
    __syncthreads();

    if (tid < 10) {
        float t = 0.f;
        for (int co = 0; co < 64; ++co) t += red[co * 10 + tid];
        atomicAdd(&ws[(set * 16 + b) * 10 + tid], t);
    }
}

// ---------------- epilogue: add b_out, write fp32 ----------------
__global__ __launch_bounds__(320) void final_bias(
    const float* __restrict__ ws, const float* __restrict__ bU,
    const float* __restrict__ bL, float* __restrict__ out)
{
    const int i = threadIdx.x;
    if (i >= 320) return;
    const int set = i / 160;
    const int r   = i - set * 160;
    const float* bin = set ? bL : bU;
    out[(set ? OUT_BL_OFF : OUT_BU_OFF) + r] = ws[i] + bin[r];
}

extern "C" void kernel_launch(void* const* d_in, const int* in_sizes, int n_in,
                              void* d_out, int out_size, void* d_ws, size_t ws_size,
                              hipStream_t stream) {
    const float* wU   = (const float*)d_in[0];
    const float* bU   = (const float*)d_in[1];
    const float* wL   = (const float*)d_in[2];
    const float* bL   = (const float*)d_in[3];
    const float* Kg   = (const float*)d_in[4];
    const float* bias = (const float*)d_in[5];
    float* out = (float*)d_out;
    float* ws  = (float*)d_ws;

    hipMemsetAsync(ws, 0, 320 * sizeof(float), stream);
    hipLaunchKernelGGL(bias_kernel, dim3(256), dim3(640), 0, stream, wU, wL, bias, ws);
    hipLaunchKernelGGL(conv_kernel, dim3(2048), dim3(256), 0, stream, wU, wL, Kg, out);
    hipLaunchKernelGGL(final_bias, dim3(1), dim3(320), 0, stream, ws, bU, bL, out);
}